// Round 15
// baseline (713.365 us; speedup 1.0000x reference)
//
#include <hip/hip_runtime.h>
#include <math.h>

#define NB 4
#define CIN 64
#define CIT 16
#define KS 7
#define PAD 3
#define HH 128
#define WW 128
#define HP 134          // 128 + 2*3
#define WPS 136         // padded row width (px)
#define L1 1024         // 32*32 query patches
#define DD 784          // 16*49
#define SCALE_F 10.0f
#define WSCR 3.5f       // screening window: 1.6 (1e-7 mass) + 2*5sigma_bf16 (~1.1) + fp16 + margin
#define TCAP 128        // surviving-tile capacity per query (expect ~2-20)
#define WEPS 1e-7f      // PV per-key skip threshold (online w only overestimates final weight)

#define NPIX (HP * WPS)             // 18,224 px per batch-plane
#define NHWCF (NB * NPIX * CIT)     // floats (or shorts) per NHWC plane set
#define RSTR 2176                   // LDS ring row stride in shorts (= WPS*CIT)
#define WROW 352                    // k_finalize window row stride in floats (22 px * 16 ch)

typedef __attribute__((ext_vector_type(4))) float f32x4;
typedef __attribute__((ext_vector_type(8))) short s16x8;
typedef __attribute__((ext_vector_type(4))) unsigned int u32x4;

__device__ __forceinline__ unsigned short f2bf(float f) {
    unsigned u = __float_as_uint(f);
    unsigned r = (u + 0x7FFFu + ((u >> 16) & 1u)) >> 16;   // RNE
    return (unsigned short)r;
}

// K1: fused 1x1 convs -> fp32 NHWC padded planes (b1f,b2f,b3f) + bf16 NHWC planes (b1n,b3n)
__global__ __launch_bounds__(256) void k_prep(
    const float* __restrict__ bin,
    const float* __restrict__ gw, const float* __restrict__ gb,
    const float* __restrict__ tw, const float* __restrict__ tb,
    const float* __restrict__ pw, const float* __restrict__ pb,
    float* __restrict__ b1f, float* __restrict__ b2f, float* __restrict__ b3f,
    unsigned short* __restrict__ b1n, unsigned short* __restrict__ b3n)
{
    int p = blockIdx.x * 256 + threadIdx.x;
    if (p >= NB * NPIX) return;
    int x = p % WPS; int r = p / WPS; int y = r % HP; int bb = r / HP;
    bool inter = (x >= PAD && x < PAD + WW && y >= PAD && y < PAD + HH);
    float v[CIN];
    if (inter) {
        int iy = y - PAD, ix = x - PAD;
        const float* src = bin + ((size_t)(bb * CIN) * HH + iy) * WW + ix;
        #pragma unroll
        for (int ci = 0; ci < CIN; ++ci) v[ci] = src[ci * HH * WW];
    }
    float a1v[CIT], a2v[CIT], a3v[CIT];
    unsigned short o1[CIT], o3[CIT];
    #pragma unroll
    for (int co = 0; co < CIT; ++co) {
        float a1 = 0.f, a2 = 0.f, a3 = 0.f;
        if (inter) {
            a1 = gb[co]; a2 = tb[co]; a3 = pb[co];
            #pragma unroll
            for (int ci = 0; ci < CIN; ++ci) {
                float vv = v[ci];
                a1 += gw[co * CIN + ci] * vv;
                a2 += tw[co * CIN + ci] * vv;
                a3 += pw[co * CIN + ci] * vv;
            }
        }
        a1v[co] = a1; a2v[co] = a2; a3v[co] = a3;
        o1[co] = f2bf(a1); o3[co] = f2bf(a3);
    }
    size_t pb16 = (size_t)p * CIT;
    #pragma unroll
    for (int g = 0; g < 4; ++g) {
        f32x4 w1 = {a1v[4*g], a1v[4*g+1], a1v[4*g+2], a1v[4*g+3]};
        f32x4 w2 = {a2v[4*g], a2v[4*g+1], a2v[4*g+2], a2v[4*g+3]};
        f32x4 w3 = {a3v[4*g], a3v[4*g+1], a3v[4*g+2], a3v[4*g+3]};
        *(f32x4*)(b1f + pb16 + 4*g) = w1;
        *(f32x4*)(b2f + pb16 + 4*g) = w2;
        *(f32x4*)(b3f + pb16 + 4*g) = w3;
    }
    unsigned pk1[8], pk3[8];
    #pragma unroll
    for (int kk = 0; kk < 8; ++kk) {
        pk1[kk] = (unsigned)o1[2 * kk] | ((unsigned)o1[2 * kk + 1] << 16);
        pk3[kk] = (unsigned)o3[2 * kk] | ((unsigned)o3[2 * kk + 1] << 16);
    }
    unsigned short* d1 = b1n + pb16;
    unsigned short* d3 = b3n + pb16;
    u32x4 w1a = {pk1[0], pk1[1], pk1[2], pk1[3]}, w1b = {pk1[4], pk1[5], pk1[6], pk1[7]};
    u32x4 w3a = {pk3[0], pk3[1], pk3[2], pk3[3]}, w3b = {pk3[4], pk3[5], pk3[6], pk3[7]};
    *(u32x4*)d1 = w1a; *(u32x4*)(d1 + 8) = w1b;
    *(u32x4*)d3 = w3a; *(u32x4*)(d3 + 8) = w3b;
}

// K2: MFMA bf16 screening, 64 QUERIES/BLOCK (4 B register sets -> each 16B A-read feeds
// 4 MFMAs, halving LDS traffic; kernel becomes MFMA-bound). Block = (batch, query row
// PAIR, ky-quarter); grid 256 = 1 block/CU, 2 waves/SIMD at ~450 VGPR (unified VGPR/AGPR).
// Q staged in two 32-query rounds (LDS unioned with K ring). 16-row K ring; 4 phases x 8
// barrier-free iterations; sync refill between phases.
// tmaxh layout: per-query-contiguous [(grp*16+qidx)][qt*256 + it*8 + w]  (fp16)
__global__ __launch_bounds__(512, 2) void k_screen(
    const unsigned short* __restrict__ b1n, const unsigned short* __restrict__ b3n,
    _Float16* __restrict__ tmaxh)
{
    int blk = blockIdx.x;           // 256 = bb(4) x qhp(16) x qt(4)
    int qt = blk & 3;
    int qhp = (blk >> 2) & 15;      // query-row pair: rows 2*qhp, 2*qhp+1
    int bb = blk >> 6;
    int qstart_ky = qt * 32;
    int tid = threadIdx.x;
    int lane = tid & 63, w = tid >> 6;   // w = kx tile 0..7
    int lanelow = lane & 15;
    int h = (lane >> 5) & 1;        // pixel parity within the K=32 chunk
    int clo = (lane >> 4) & 1;      // channel half

    __shared__ __align__(16) short smem[16 * RSTR];   // 69.6KB: Q staging union K ring

    const unsigned short* b1nb = b1n + (size_t)bb * (NPIX * CIT);
    const unsigned short* b3nb = b3n + (size_t)bb * (NPIX * CIT);

    // per-query tmax bases: set S covers queries (4*qhp+S)*16 .. +15 of this batch
    size_t qb0 = ((size_t)((bb * 64 + 4 * qhp + 0) * 16 + lanelow)) * 1024 + qt * 256 + w;
    size_t qb1 = ((size_t)((bb * 64 + 4 * qhp + 1) * 16 + lanelow)) * 1024 + qt * 256 + w;
    size_t qb2 = ((size_t)((bb * 64 + 4 * qhp + 2) * 16 + lanelow)) * 1024 + qt * 256 + w;
    size_t qb3 = ((size_t)((bb * 64 + 4 * qhp + 3) * 16 + lanelow)) * 1024 + qt * 256 + w;

    s16x8 B0[25], B1[25], B2[25], B3[25];
    int koff = ((lane >> 4) & 3) * 8;

    // ---- staging round A: 32 queries of row 2*qhp ----
    {
        int qybase = 8 * qhp;
        for (int task = tid; task < 1600; task += 512) {
            int pp = task % 50, qq = task / 50;
            u32x4 lo = {0, 0, 0, 0}, hi = {0, 0, 0, 0};
            if (pp < 49) {
                int i = pp / 7, j = pp % 7;
                int qx = 4 * qq;
                const unsigned short* src = b1nb + ((size_t)(qybase + i) * WPS + qx + j) * CIT;
                lo = *(const u32x4*)src; hi = *(const u32x4*)(src + 8);
            }
            short* dst = smem + (qq * 50 + pp) * 16;
            *(u32x4*)dst = lo; *(u32x4*)(dst + 8) = hi;
        }
        __syncthreads();
        #pragma unroll
        for (int s = 0; s < 25; ++s) {
            int ko = s * 32 + koff;
            B0[s] = *(const s16x8*)(smem + lanelow * 800 + ko);
            B1[s] = *(const s16x8*)(smem + (lanelow + 16) * 800 + ko);
        }
        __syncthreads();
    }
    // ---- staging round B: 32 queries of row 2*qhp+1 ----
    {
        int qybase = 8 * qhp + 4;
        for (int task = tid; task < 1600; task += 512) {
            int pp = task % 50, qq = task / 50;
            u32x4 lo = {0, 0, 0, 0}, hi = {0, 0, 0, 0};
            if (pp < 49) {
                int i = pp / 7, j = pp % 7;
                int qx = 4 * qq;
                const unsigned short* src = b1nb + ((size_t)(qybase + i) * WPS + qx + j) * CIT;
                lo = *(const u32x4*)src; hi = *(const u32x4*)(src + 8);
            }
            short* dst = smem + (qq * 50 + pp) * 16;
            *(u32x4*)dst = lo; *(u32x4*)(dst + 8) = hi;
        }
        __syncthreads();
        #pragma unroll
        for (int s = 0; s < 25; ++s) {
            int ko = s * 32 + koff;
            B2[s] = *(const s16x8*)(smem + lanelow * 800 + ko);
            B3[s] = *(const s16x8*)(smem + (lanelow + 16) * 800 + ko);
        }
        __syncthreads();
    }

    short* kring = smem;    // 16 row slots x 136 px x 16 ch (full padded rows)
    // initial fill: rows qstart..qstart+15 (slot = row & 15 = rr)
    for (int task = tid; task < 16 * 272; task += 512) {
        int rr = task / 272, ch = task % 272;
        *(u32x4*)(kring + rr * RSTR + ch * 8) =
            *(const u32x4*)(b3nb + (size_t)(qstart_ky + rr) * (WPS * CIT) + ch * 8);
    }
    __syncthreads();

    int abase = (w * 16 + lanelow) * 16 + clo * 8;

    for (int p = 0; p < 4; ++p) {
        __builtin_amdgcn_s_setprio(1);
        for (int it8 = 0; it8 < 8; ++it8) {
            int it = 8 * p + it8;
            int ky = qstart_ky + it;
            f32x4 C0 = {0.f, 0.f, 0.f, 0.f}, C1 = {0.f, 0.f, 0.f, 0.f};
            f32x4 C2 = {0.f, 0.f, 0.f, 0.f}, C3 = {0.f, 0.f, 0.f, 0.f};
            #pragma unroll
            for (int s = 0; s < 25; ++s) {
                const int pe = 2 * s;
                const int po = (2 * s + 1 < 49) ? (2 * s + 1) : 0;  // s=24 odd slot: B is zero
                const int ie = pe / 7, je = pe % 7;
                const int io = po / 7, jo = po % 7;
                int i_h = h ? io : ie;
                int j_h = h ? jo : je;
                int slot = (ky + i_h) & 15;
                const short* ap = kring + slot * RSTR + j_h * 16 + abase;
                s16x8 a0 = *(const s16x8*)ap;
                C0 = __builtin_amdgcn_mfma_f32_16x16x32_bf16(a0, B0[s], C0, 0, 0, 0);
                C1 = __builtin_amdgcn_mfma_f32_16x16x32_bf16(a0, B1[s], C1, 0, 0, 0);
                C2 = __builtin_amdgcn_mfma_f32_16x16x32_bf16(a0, B2[s], C2, 0, 0, 0);
                C3 = __builtin_amdgcn_mfma_f32_16x16x32_bf16(a0, B3[s], C3, 0, 0, 0);
            }
            float lm0 = fmaxf(fmaxf(C0[0], C0[1]), fmaxf(C0[2], C0[3]));
            lm0 = fmaxf(lm0, __shfl_xor(lm0, 16));
            lm0 = fmaxf(lm0, __shfl_xor(lm0, 32));
            float lm1 = fmaxf(fmaxf(C1[0], C1[1]), fmaxf(C1[2], C1[3]));
            lm1 = fmaxf(lm1, __shfl_xor(lm1, 16));
            lm1 = fmaxf(lm1, __shfl_xor(lm1, 32));
            float lm2 = fmaxf(fmaxf(C2[0], C2[1]), fmaxf(C2[2], C2[3]));
            lm2 = fmaxf(lm2, __shfl_xor(lm2, 16));
            lm2 = fmaxf(lm2, __shfl_xor(lm2, 32));
            float lm3 = fmaxf(fmaxf(C3[0], C3[1]), fmaxf(C3[2], C3[3]));
            lm3 = fmaxf(lm3, __shfl_xor(lm3, 16));
            lm3 = fmaxf(lm3, __shfl_xor(lm3, 32));
            if (lane < 16) {
                tmaxh[qb0 + it * 8] = (_Float16)lm0;
                tmaxh[qb1 + it * 8] = (_Float16)lm1;
                tmaxh[qb2 + it * 8] = (_Float16)lm2;
                tmaxh[qb3 + it * 8] = (_Float16)lm3;
            }
        }
        __builtin_amdgcn_s_setprio(0);
        __syncthreads();    // all waves done reading this phase's ring rows
        if (p < 3) {
            // refill rows qstart+8p+16 .. +23 into slots (row & 15)
            int rbase = qstart_ky + 8 * p + 16;
            for (int task = tid; task < 8 * 272; task += 512) {
                int rr = task / 272, ch = task % 272;
                int row = rbase + rr;
                int srow = (row < HP) ? row : (HP - 1);   // clamp (clamped rows never read)
                *(u32x4*)(kring + (row & 15) * RSTR + ch * 8) =
                    *(const u32x4*)(b3nb + (size_t)srow * (WPS * CIT) + ch * 8);
            }
            __syncthreads();    // new rows visible
        }
    }
}

// K3: scan tile maxima, select tiles >= max - WSCR. Per surviving TILE: K window ->
// per-wave LDS buffer (T14 pipelined); scores from LDS (exact fp32); online softmax;
// V loaded per-KEY only when w > WEPS. One wave per query. Zp pixel-major d = 16*p + c.
__global__ __launch_bounds__(256) void k_finalize(
    const float* __restrict__ b1f, const float* __restrict__ b2f,
    const float* __restrict__ b3f, const _Float16* __restrict__ tmaxh,
    float* __restrict__ Zp)
{
    int wv = threadIdx.x >> 6;
    int lane = threadIdx.x & 63;
    int gq = blockIdx.x * 4 + wv;
    int bb = gq >> 10, q = gq & 1023;
    int qh = q >> 5, qw = q & 31;
    int qy = qh * 4, qx = qw * 4;
    int ch = lane & 15, pbase = lane >> 4;

    __shared__ int tq[4][TCAP];
    __shared__ __align__(16) float wbufs[4][7 * WROW];   // per-wave K window [row][x 0..21][ch]

    const float* b1b = b1f + (size_t)bb * (NPIX * CIT);
    const float* b2b = b2f + (size_t)bb * (NPIX * CIT);
    const float* b3b = b3f + (size_t)bb * (NPIX * CIT);

    // scan this query's 1024 tile maxima (contiguous 2KB; lane covers elems lane*16..+15)
    const _Float16* qb = tmaxh + ((size_t)((bb * 64 + (q >> 4)) * 16 + (q & 15))) * 1024;
    _Float16 tvh[16];
    *(u32x4*)&tvh[0] = *(const u32x4*)(qb + (size_t)lane * 16);
    *(u32x4*)&tvh[8] = *(const u32x4*)(qb + (size_t)lane * 16 + 8);
    float tv[16]; float mg = -1e30f;
    #pragma unroll
    for (int k = 0; k < 16; ++k) {
        tv[k] = (float)tvh[k];
        mg = fmaxf(mg, tv[k]);
    }
    #pragma unroll
    for (int o = 32; o > 0; o >>= 1) mg = fmaxf(mg, __shfl_xor(mg, o));
    float thr = mg - WSCR;

    // deterministic survivor-tile list via ballot-scan (order: k-major, lane-minor)
    int cnt = 0;
    #pragma unroll
    for (int k = 0; k < 16; ++k) {
        bool p = (tv[k] >= thr);
        unsigned long long mk = __ballot(p);
        if (p) {
            int pos = cnt + (int)__popcll(mk & ((1ull << lane) - 1ull));
            if (pos < TCAP) tq[wv][pos] = lane * 16 + k;   // e = qt*256 + kyl*8 + t
        }
        cnt += (int)__popcll(mk);
    }
    int nt = min(cnt, TCAP);
    __syncthreads();

    // loop-invariant window task decomposition (10 slots/lane)
    int wrow[10], wxf[10]; bool wok[10];
    #pragma unroll
    for (int t = 0; t < 10; ++t) {
        int task = lane + 64 * t;
        wok[t] = (task < 616);
        wrow[t] = (task < 616) ? (task / 88) : 0;
        wxf[t] = (task < 616) ? ((task % 88) * 4) : 0;
    }

    // per-lane patch slots (NHWC): lane handles pixels p = pbase+4k, channel ch
    float qreg[13]; int offs[13]; int loff[13];
    int qorg = (qy * WPS + qx) * CIT;
    #pragma unroll
    for (int k = 0; k < 13; ++k) {
        int p = pbase + 4 * k;
        if (p < 49) {
            int pi = p / 7, pj = p % 7;
            offs[k] = (pi * WPS + pj) * CIT + ch;   // global offset (V loads)
            loff[k] = pi * WROW + pj * CIT + ch;    // LDS window offset
            qreg[k] = b1b[qorg + offs[k]];
        } else { offs[k] = 0; loff[k] = 0; qreg[k] = 0.f; }
    }
    float* wbuf = wbufs[wv];

    float m = -1e30f, l = 0.f, acc[13];
    #pragma unroll
    for (int k = 0; k < 13; ++k) acc[k] = 0.f;

    // prologue: prefetch tile 0's window into regs
    f32x4 pf[10];
    if (nt > 0) {
        int e0 = tq[wv][0];
        const float* ws0 = b3b + (size_t)((e0 >> 3) * WPS + (e0 & 7) * 16) * CIT;
        #pragma unroll
        for (int t = 0; t < 10; ++t)
            if (wok[t]) pf[t] = *(const f32x4*)(ws0 + (size_t)wrow[t] * (WPS * CIT) + wxf[t]);
    }

    for (int ti = 0; ti < nt; ++ti) {
        int e = tq[wv][ti];
        int ky = e >> 3;
        int kxb = (e & 7) * 16;
        // commit prefetched window to LDS (ds_write consumes pf at issue)
        #pragma unroll
        for (int t = 0; t < 10; ++t)
            if (wok[t]) *(f32x4*)(wbuf + wrow[t] * WROW + wxf[t]) = pf[t];
        // issue NEXT tile's loads now; they fly during this tile's compute
        if (ti + 1 < nt) {
            int e2 = tq[wv][ti + 1];
            const float* ws2 = b3b + (size_t)((e2 >> 3) * WPS + (e2 & 7) * 16) * CIT;
            #pragma unroll
            for (int t = 0; t < 10; ++t)
                if (wok[t]) pf[t] = *(const f32x4*)(ws2 + (size_t)wrow[t] * (WPS * CIT) + wxf[t]);
        }
        // per-wave buffer: no barrier; compiler orders lgkm before first LDS read
        for (int c4 = 0; c4 < 4; ++c4) {
            float kvv[4][13];
            #pragma unroll
            for (int u = 0; u < 4; ++u) {
                int cib = (c4 * 4 + u) * CIT;
                #pragma unroll
                for (int k = 0; k < 13; ++k) kvv[u][k] = wbuf[loff[k] + cib];
            }
            float s[4];
            #pragma unroll
            for (int u = 0; u < 4; ++u) {
                float t = 0.f;
                #pragma unroll
                for (int k = 0; k < 13; ++k) t += qreg[k] * kvv[u][k];
                #pragma unroll
                for (int o = 32; o > 0; o >>= 1) t += __shfl_xor(t, o);
                s[u] = t;
            }
            float mnew = fmaxf(m, fmaxf(fmaxf(s[0], s[1]), fmaxf(s[2], s[3])));
            float sc = __expf(SCALE_F * (m - mnew));   // exp(-inf)=0 first chunk; ==1 if no new max
            float wk[4];
            wk[0] = __expf(SCALE_F * (s[0] - mnew));
            wk[1] = __expf(SCALE_F * (s[1] - mnew));
            wk[2] = __expf(SCALE_F * (s[2] - mnew));
            wk[3] = __expf(SCALE_F * (s[3] - mnew));
            l = l * sc + (wk[0] + wk[1] + wk[2] + wk[3]);
            m = mnew;
            float wmx = fmaxf(fmaxf(wk[0], wk[1]), fmaxf(wk[2], wk[3]));   // wave-uniform
            if (wmx > WEPS) {
                // skipped chunks have mnew==m_old so sc==1: rescale only needed here
                #pragma unroll
                for (int k = 0; k < 13; ++k) acc[k] *= sc;
                #pragma unroll
                for (int u = 0; u < 4; ++u) {
                    if (wk[u] > WEPS) {
                        int kb = (ky * WPS + kxb + c4 * 4 + u) * CIT;
                        #pragma unroll
                        for (int k = 0; k < 13; ++k) acc[k] += wk[u] * b2b[kb + offs[k]];
                    }
                }
            }
        }
    }

    float inv = (nt > 0) ? (1.f / l) : 0.f;
    float* zq = Zp + (size_t)gq * DD;
    #pragma unroll
    for (int k = 0; k < 13; ++k) {
        int d = lane + 64 * k;       // d = 16*p + ch (pixel-major)
        if (d < DD) zq[d] = acc[k] * inv;
    }
}

// K4: fold (overlap-add) + count-divide + 1x1 out conv + residual.
// Zp layout [gq][d] with d = 16*(i*7+j) + c  -> 16-consecutive-float reads per position.
__global__ __launch_bounds__(256) void k_fold(
    const float* __restrict__ bin, const float* __restrict__ ow,
    const float* __restrict__ ob, const float* __restrict__ Zp,
    float* __restrict__ outp)
{
    int p = blockIdx.x * 256 + threadIdx.x;
    if (p >= NB * HH * WW) return;
    int ox = p % WW; int r = p / WW; int oy = r % HH; int bb = r / HH;
    int yp = oy + PAD, xp = ox + PAD;
    int qh0 = (yp - 3) >> 2, qh1 = min(31, yp >> 2);
    int qw0 = (xp - 3) >> 2, qw1 = min(31, xp >> 2);
    float cnt = (float)((qh1 - qh0 + 1) * (qw1 - qw0 + 1));
    float y16[CIT];
    #pragma unroll
    for (int c = 0; c < CIT; ++c) y16[c] = 0.f;
    for (int qhh = qh0; qhh <= qh1; ++qhh) {
        int i = yp - 4 * qhh;
        for (int qww = qw0; qww <= qw1; ++qww) {
            int j = xp - 4 * qww;
            const float* zb = Zp + (size_t)((bb << 10) + qhh * 32 + qww) * DD + (i * 7 + j) * CIT;
            #pragma unroll
            for (int c = 0; c < CIT; ++c) y16[c] += zb[c];
        }
    }
    float icnt = 1.f / cnt;
    #pragma unroll
    for (int c = 0; c < CIT; ++c) y16[c] *= icnt;
    size_t oidx = ((size_t)(bb * CIN) * HH + oy) * WW + ox;
    for (int co = 0; co < CIN; ++co) {
        float a = ob[co];
        #pragma unroll
        for (int c = 0; c < CIT; ++c) a += ow[co * CIT + c] * y16[c];
        outp[oidx + (size_t)co * HH * WW] = bin[oidx + (size_t)co * HH * WW] + a;
    }
}

extern "C" void kernel_launch(void* const* d_in, const int* in_sizes, int n_in,
                              void* d_out, int out_size, void* d_ws, size_t ws_size,
                              hipStream_t stream) {
    (void)in_sizes; (void)n_in; (void)out_size; (void)ws_size;
    const float* bin = (const float*)d_in[0];
    const float* gw  = (const float*)d_in[1];
    const float* gb  = (const float*)d_in[2];
    const float* tw  = (const float*)d_in[3];
    const float* tb  = (const float*)d_in[4];
    const float* pw  = (const float*)d_in[5];
    const float* pb  = (const float*)d_in[6];
    const float* ow  = (const float*)d_in[7];
    const float* ob  = (const float*)d_in[8];

    float* outp = (float*)d_out;
    // d_out scratch (consumed before k_fold writes outp): 14.0 MB of 16.78 MB
    float* b3f = outp;                                        // NHWCF floats
    float* b1f = outp + NHWCF;                                // NHWCF floats
    unsigned short* b3n = (unsigned short*)(outp + 2 * (size_t)NHWCF);  // NHWCF shorts
    unsigned short* b1n = b3n + NHWCF;                        // NHWCF shorts

    float* ws = (float*)d_ws;                                 // 25.9 MB total
    float* b2f = ws;                                          // NHWCF floats
    float* Zp  = ws + NHWCF;                                  // NB*L1*DD floats
    _Float16* tmaxh = (_Float16*)(ws + NHWCF + (size_t)NB * L1 * DD);  // 4096*1024 fp16

    hipLaunchKernelGGL(k_prep, dim3((NB * NPIX + 255) / 256), dim3(256), 0, stream,
                       bin, gw, gb, tw, tb, pw, pb, b1f, b2f, b3f, b1n, b3n);
    hipLaunchKernelGGL(k_screen, dim3(256), dim3(512), 0, stream,
                       b1n, b3n, tmaxh);
    hipLaunchKernelGGL(k_finalize, dim3(1024), dim3(256), 0, stream,
                       b1f, b2f, b3f, tmaxh, Zp);
    hipLaunchKernelGGL(k_fold, dim3((NB * HH * WW + 255) / 256), dim3(256), 0, stream,
                       bin, ow, ob, Zp, outp);
}

// Round 16
// 211.720 us; speedup vs baseline: 3.3694x; 3.3694x over previous
//
#include <hip/hip_runtime.h>
#include <math.h>

#define NB 4
#define CIN 64
#define CIT 16
#define KS 7
#define PAD 3
#define HH 128
#define WW 128
#define HP 134          // 128 + 2*3
#define WPS 136         // padded row width (px)
#define L1 1024         // 32*32 query patches
#define DD 784          // 16*49
#define SCALE_F 10.0f
#define WSCR 3.5f       // screening window: 1.6 (1e-7 mass) + 2*5sigma_bf16 (~1.1) + fp16 + margin
#define TCAP 128        // surviving-tile capacity per query (expect ~2-20)
#define WEPS 1e-7f      // PV per-key skip threshold (online w only overestimates final weight)

#define NPIX (HP * WPS)             // 18,224 px per batch-plane
#define NHWCF (NB * NPIX * CIT)     // floats (or shorts) per NHWC plane set
#define RSTR 2176                   // LDS ring row stride in shorts (= WPS*CIT)
#define WROW 352                    // k_finalize window row stride in floats (22 px * 16 ch)

typedef __attribute__((ext_vector_type(4))) float f32x4;
typedef __attribute__((ext_vector_type(8))) short s16x8;
typedef __attribute__((ext_vector_type(4))) unsigned int u32x4;

__device__ __forceinline__ unsigned short f2bf(float f) {
    unsigned u = __float_as_uint(f);
    unsigned r = (u + 0x7FFFu + ((u >> 16) & 1u)) >> 16;   // RNE
    return (unsigned short)r;
}

// K1: fused 1x1 convs -> fp32 NHWC padded planes (b1f,b2f,b3f) + bf16 NHWC planes (b1n,b3n)
__global__ __launch_bounds__(256) void k_prep(
    const float* __restrict__ bin,
    const float* __restrict__ gw, const float* __restrict__ gb,
    const float* __restrict__ tw, const float* __restrict__ tb,
    const float* __restrict__ pw, const float* __restrict__ pb,
    float* __restrict__ b1f, float* __restrict__ b2f, float* __restrict__ b3f,
    unsigned short* __restrict__ b1n, unsigned short* __restrict__ b3n)
{
    int p = blockIdx.x * 256 + threadIdx.x;
    if (p >= NB * NPIX) return;
    int x = p % WPS; int r = p / WPS; int y = r % HP; int bb = r / HP;
    bool inter = (x >= PAD && x < PAD + WW && y >= PAD && y < PAD + HH);
    float v[CIN];
    if (inter) {
        int iy = y - PAD, ix = x - PAD;
        const float* src = bin + ((size_t)(bb * CIN) * HH + iy) * WW + ix;
        #pragma unroll
        for (int ci = 0; ci < CIN; ++ci) v[ci] = src[ci * HH * WW];
    }
    float a1v[CIT], a2v[CIT], a3v[CIT];
    unsigned short o1[CIT], o3[CIT];
    #pragma unroll
    for (int co = 0; co < CIT; ++co) {
        float a1 = 0.f, a2 = 0.f, a3 = 0.f;
        if (inter) {
            a1 = gb[co]; a2 = tb[co]; a3 = pb[co];
            #pragma unroll
            for (int ci = 0; ci < CIN; ++ci) {
                float vv = v[ci];
                a1 += gw[co * CIN + ci] * vv;
                a2 += tw[co * CIN + ci] * vv;
                a3 += pw[co * CIN + ci] * vv;
            }
        }
        a1v[co] = a1; a2v[co] = a2; a3v[co] = a3;
        o1[co] = f2bf(a1); o3[co] = f2bf(a3);
    }
    size_t pb16 = (size_t)p * CIT;
    #pragma unroll
    for (int g = 0; g < 4; ++g) {
        f32x4 w1 = {a1v[4*g], a1v[4*g+1], a1v[4*g+2], a1v[4*g+3]};
        f32x4 w2 = {a2v[4*g], a2v[4*g+1], a2v[4*g+2], a2v[4*g+3]};
        f32x4 w3 = {a3v[4*g], a3v[4*g+1], a3v[4*g+2], a3v[4*g+3]};
        *(f32x4*)(b1f + pb16 + 4*g) = w1;
        *(f32x4*)(b2f + pb16 + 4*g) = w2;
        *(f32x4*)(b3f + pb16 + 4*g) = w3;
    }
    unsigned pk1[8], pk3[8];
    #pragma unroll
    for (int kk = 0; kk < 8; ++kk) {
        pk1[kk] = (unsigned)o1[2 * kk] | ((unsigned)o1[2 * kk + 1] << 16);
        pk3[kk] = (unsigned)o3[2 * kk] | ((unsigned)o3[2 * kk + 1] << 16);
    }
    unsigned short* d1 = b1n + pb16;
    unsigned short* d3 = b3n + pb16;
    u32x4 w1a = {pk1[0], pk1[1], pk1[2], pk1[3]}, w1b = {pk1[4], pk1[5], pk1[6], pk1[7]};
    u32x4 w3a = {pk3[0], pk3[1], pk3[2], pk3[3]}, w3b = {pk3[4], pk3[5], pk3[6], pk3[7]};
    *(u32x4*)d1 = w1a; *(u32x4*)(d1 + 8) = w1b;
    *(u32x4*)d3 = w3a; *(u32x4*)(d3 + 8) = w3b;
}

// K2: MFMA bf16 screening (round-12 structure, known 100.2us). Block = (batch, query ROW
// of 32, ky-quarter). 16-row K ring; 4 phases x 8 barrier-free iterations; sync refill.
// tmaxh layout: per-query-contiguous [(grp*16+qidx)][qt*256 + it*8 + w]  (fp16)
__global__ __launch_bounds__(512, 2) void k_screen(
    const unsigned short* __restrict__ b1n, const unsigned short* __restrict__ b3n,
    _Float16* __restrict__ tmaxh)
{
    int blk = blockIdx.x;           // 512 = bb(4) x qh(32) x qt(4)
    int qt = blk & 3;
    int qh = (blk >> 2) & 31;
    int bb = blk >> 7;
    int qstart_ky = qt * 32;
    int tid = threadIdx.x;
    int lane = tid & 63, w = tid >> 6;   // w = kx tile 0..7
    int lanelow = lane & 15;
    int h = (lane >> 5) & 1;        // pixel parity within the K=32 chunk
    int clo = (lane >> 4) & 1;      // channel half

    __shared__ __align__(16) short smem[16 * RSTR];   // 69.6KB: Q staging union K ring

    const unsigned short* b1nb = b1n + (size_t)bb * (NPIX * CIT);
    const unsigned short* b3nb = b3n + (size_t)bb * (NPIX * CIT);

    int qybase = 4 * qh;
    // per-query tmax bases (this wave's lanes 0..15 = queries of each set)
    size_t qb0 = ((size_t)((bb * 64 + 2 * qh) * 16 + lanelow)) * 1024 + qt * 256 + w;
    size_t qb1 = ((size_t)((bb * 64 + 2 * qh + 1) * 16 + lanelow)) * 1024 + qt * 256 + w;

    // stage Q: 32 queries x 50 pixels x 32B (pixel 49 = zeros)
    for (int task = tid; task < 1600; task += 512) {
        int pp = task % 50, qq = task / 50;
        u32x4 lo = {0, 0, 0, 0}, hi = {0, 0, 0, 0};
        if (pp < 49) {
            int i = pp / 7, j = pp % 7;
            int qx = 4 * qq;
            const unsigned short* src = b1nb + ((size_t)(qybase + i) * WPS + qx + j) * CIT;
            lo = *(const u32x4*)src; hi = *(const u32x4*)(src + 8);
        }
        short* dst = smem + (qq * 50 + pp) * 16;
        *(u32x4*)dst = lo; *(u32x4*)(dst + 8) = hi;
    }
    __syncthreads();

    // B fragments: two query sets -> registers/AGPRs
    s16x8 B0[25], B1[25];
    #pragma unroll
    for (int s = 0; s < 25; ++s) {
        int ko = s * 32 + ((lane >> 4) & 3) * 8;
        B0[s] = *(const s16x8*)(smem + lanelow * 800 + ko);
        B1[s] = *(const s16x8*)(smem + (lanelow + 16) * 800 + ko);
    }
    __syncthreads();   // all waves done reading Q before ring overwrites smem

    short* kring = smem;    // 16 row slots x 136 px x 16 ch (full padded rows)
    // initial fill: rows qstart..qstart+15 (slot = row & 15 = rr)
    for (int task = tid; task < 16 * 272; task += 512) {
        int rr = task / 272, ch = task % 272;
        *(u32x4*)(kring + rr * RSTR + ch * 8) =
            *(const u32x4*)(b3nb + (size_t)(qstart_ky + rr) * (WPS * CIT) + ch * 8);
    }
    __syncthreads();

    int abase = (w * 16 + lanelow) * 16 + clo * 8;

    for (int p = 0; p < 4; ++p) {
        __builtin_amdgcn_s_setprio(1);
        for (int it8 = 0; it8 < 8; ++it8) {
            int it = 8 * p + it8;
            int ky = qstart_ky + it;
            f32x4 C0 = {0.f, 0.f, 0.f, 0.f}, C1 = {0.f, 0.f, 0.f, 0.f};
            #pragma unroll
            for (int s = 0; s < 25; ++s) {
                const int pe = 2 * s;
                const int po = (2 * s + 1 < 49) ? (2 * s + 1) : 0;  // s=24 odd slot: B is zero
                const int ie = pe / 7, je = pe % 7;
                const int io = po / 7, jo = po % 7;
                int i_h = h ? io : ie;
                int j_h = h ? jo : je;
                int slot = (ky + i_h) & 15;
                const short* ap = kring + slot * RSTR + j_h * 16 + abase;
                s16x8 a0 = *(const s16x8*)ap;
                C0 = __builtin_amdgcn_mfma_f32_16x16x32_bf16(a0, B0[s], C0, 0, 0, 0);
                C1 = __builtin_amdgcn_mfma_f32_16x16x32_bf16(a0, B1[s], C1, 0, 0, 0);
            }
            float lm0 = fmaxf(fmaxf(C0[0], C0[1]), fmaxf(C0[2], C0[3]));
            lm0 = fmaxf(lm0, __shfl_xor(lm0, 16));
            lm0 = fmaxf(lm0, __shfl_xor(lm0, 32));
            float lm1 = fmaxf(fmaxf(C1[0], C1[1]), fmaxf(C1[2], C1[3]));
            lm1 = fmaxf(lm1, __shfl_xor(lm1, 16));
            lm1 = fmaxf(lm1, __shfl_xor(lm1, 32));
            if (lane < 16) {
                tmaxh[qb0 + it * 8] = (_Float16)lm0;
                tmaxh[qb1 + it * 8] = (_Float16)lm1;
            }
        }
        __builtin_amdgcn_s_setprio(0);
        __syncthreads();    // all waves done reading this phase's ring rows
        if (p < 3) {
            // refill rows qstart+8p+16 .. +23 into slots (row & 15)
            int rbase = qstart_ky + 8 * p + 16;
            for (int task = tid; task < 8 * 272; task += 512) {
                int rr = task / 272, ch = task % 272;
                int row = rbase + rr;
                int srow = (row < HP) ? row : (HP - 1);   // clamp (clamped rows never read)
                *(u32x4*)(kring + (row & 15) * RSTR + ch * 8) =
                    *(const u32x4*)(b3nb + (size_t)srow * (WPS * CIT) + ch * 8);
            }
            __syncthreads();    // new rows visible
        }
    }
}

// K3: scan tile maxima, select tiles >= max - WSCR. Per surviving TILE: K window ->
// per-wave LDS buffer; VECTORIZED lane decomposition: lane = (pixel-group pg, channel-quad
// cq); slot k covers pixel px = pg+16k (<49), channels 4cq..4cq+3 -> all K/V/Q/Zp accesses
// are aligned f32x4 (ds_read_b128 / global b128). Exact fp32 online softmax; V loaded
// per-KEY only when w > WEPS. One wave per query. Zp pixel-major d = 16*px + c.
__global__ __launch_bounds__(256) void k_finalize(
    const float* __restrict__ b1f, const float* __restrict__ b2f,
    const float* __restrict__ b3f, const _Float16* __restrict__ tmaxh,
    float* __restrict__ Zp)
{
    int wv = threadIdx.x >> 6;
    int lane = threadIdx.x & 63;
    int gq = blockIdx.x * 4 + wv;
    int bb = gq >> 10, q = gq & 1023;
    int qh = q >> 5, qw = q & 31;
    int qy = qh * 4, qx = qw * 4;
    int ch4 = (lane & 3) * 4;       // channel quad start
    int pg = lane >> 2;             // pixel group 0..15

    __shared__ int tq[4][TCAP];
    __shared__ __align__(16) float wbufs[4][7 * WROW];   // per-wave K window [row][x 0..21][ch]

    const float* b1b = b1f + (size_t)bb * (NPIX * CIT);
    const float* b2b = b2f + (size_t)bb * (NPIX * CIT);
    const float* b3b = b3f + (size_t)bb * (NPIX * CIT);

    // scan this query's 1024 tile maxima (contiguous 2KB; lane covers elems lane*16..+15)
    const _Float16* qb = tmaxh + ((size_t)((bb * 64 + (q >> 4)) * 16 + (q & 15))) * 1024;
    _Float16 tvh[16];
    *(u32x4*)&tvh[0] = *(const u32x4*)(qb + (size_t)lane * 16);
    *(u32x4*)&tvh[8] = *(const u32x4*)(qb + (size_t)lane * 16 + 8);
    float tv[16]; float mg = -1e30f;
    #pragma unroll
    for (int k = 0; k < 16; ++k) {
        tv[k] = (float)tvh[k];
        mg = fmaxf(mg, tv[k]);
    }
    #pragma unroll
    for (int o = 32; o > 0; o >>= 1) mg = fmaxf(mg, __shfl_xor(mg, o));
    float thr = mg - WSCR;

    // deterministic survivor-tile list via ballot-scan (order: k-major, lane-minor)
    int cnt = 0;
    #pragma unroll
    for (int k = 0; k < 16; ++k) {
        bool p = (tv[k] >= thr);
        unsigned long long mk = __ballot(p);
        if (p) {
            int pos = cnt + (int)__popcll(mk & ((1ull << lane) - 1ull));
            if (pos < TCAP) tq[wv][pos] = lane * 16 + k;   // e = qt*256 + kyl*8 + t
        }
        cnt += (int)__popcll(mk);
    }
    int nt = min(cnt, TCAP);
    __syncthreads();

    // per-lane vector slots (NHWC): slot k -> pixel px = pg+16k, channels ch4..ch4+3
    f32x4 qreg4[4]; int offs4[4], loff4[4]; bool pok[4];
    int qorg = (qy * WPS + qx) * CIT;
    #pragma unroll
    for (int k = 0; k < 4; ++k) {
        int px = pg + 16 * k;
        pok[k] = (px < 49);
        if (pok[k]) {
            int pi = px / 7, pj = px % 7;
            offs4[k] = (pi * WPS + pj) * CIT + ch4;   // global offset (V loads)
            loff4[k] = pi * WROW + pj * CIT + ch4;    // LDS window offset
            qreg4[k] = *(const f32x4*)(b1b + qorg + offs4[k]);
        } else {
            offs4[k] = 0; loff4[k] = 0;
            qreg4[k] = (f32x4){0.f, 0.f, 0.f, 0.f};   // zero Q -> no dot contribution
        }
    }
    float* wbuf = wbufs[wv];

    float m = -1e30f, l = 0.f;
    f32x4 acc4[4];
    #pragma unroll
    for (int k = 0; k < 4; ++k) acc4[k] = (f32x4){0.f, 0.f, 0.f, 0.f};

    for (int ti = 0; ti < nt; ++ti) {
        int e = tq[wv][ti];
        int ky = e >> 3;
        int kxb = (e & 7) * 16;
        // load K window: 7 rows x 22 px x 16 ch fp32 (rows contiguous, 88 f32x4 each)
        const float* wsrc = b3b + (size_t)(ky * WPS + kxb) * CIT;
        #pragma unroll
        for (int t = 0; t < 10; ++t) {
            int task = lane + 64 * t;
            if (task < 616) {
                int row = task / 88, xf = (task % 88) * 4;
                *(f32x4*)(wbuf + row * WROW + xf) =
                    *(const f32x4*)(wsrc + (size_t)row * (WPS * CIT) + xf);
            }
        }
        // per-wave buffer: no barrier; compiler orders lgkm before first LDS read
        for (int c4 = 0; c4 < 4; ++c4) {
            f32x4 kv4[4][4];
            #pragma unroll
            for (int u = 0; u < 4; ++u) {
                int cib = (c4 * 4 + u) * CIT;
                #pragma unroll
                for (int k = 0; k < 4; ++k)
                    kv4[u][k] = *(const f32x4*)(wbuf + loff4[k] + cib);
            }
            float s[4];
            #pragma unroll
            for (int u = 0; u < 4; ++u) {
                float t = 0.f;
                #pragma unroll
                for (int k = 0; k < 4; ++k) {
                    t += qreg4[k][0] * kv4[u][k][0];
                    t += qreg4[k][1] * kv4[u][k][1];
                    t += qreg4[k][2] * kv4[u][k][2];
                    t += qreg4[k][3] * kv4[u][k][3];
                }
                #pragma unroll
                for (int o = 32; o > 0; o >>= 1) t += __shfl_xor(t, o);
                s[u] = t;
            }
            float mnew = fmaxf(m, fmaxf(fmaxf(s[0], s[1]), fmaxf(s[2], s[3])));
            float sc = __expf(SCALE_F * (m - mnew));   // exp(-inf)=0 first chunk; ==1 if no new max
            float wk[4];
            wk[0] = __expf(SCALE_F * (s[0] - mnew));
            wk[1] = __expf(SCALE_F * (s[1] - mnew));
            wk[2] = __expf(SCALE_F * (s[2] - mnew));
            wk[3] = __expf(SCALE_F * (s[3] - mnew));
            l = l * sc + (wk[0] + wk[1] + wk[2] + wk[3]);
            m = mnew;
            float wmx = fmaxf(fmaxf(wk[0], wk[1]), fmaxf(wk[2], wk[3]));   // wave-uniform
            if (wmx > WEPS) {
                // skipped chunks have mnew==m_old so sc==1: rescale only needed here
                #pragma unroll
                for (int k = 0; k < 4; ++k) acc4[k] *= sc;
                #pragma unroll
                for (int u = 0; u < 4; ++u) {
                    if (wk[u] > WEPS) {
                        int kb = (ky * WPS + kxb + c4 * 4 + u) * CIT;
                        #pragma unroll
                        for (int k = 0; k < 4; ++k) {
                            f32x4 vv = *(const f32x4*)(b2b + kb + offs4[k]);
                            acc4[k] += wk[u] * vv;
                        }
                    }
                }
            }
        }
    }

    float inv = (nt > 0) ? (1.f / l) : 0.f;
    float* zq = Zp + (size_t)gq * DD;
    #pragma unroll
    for (int k = 0; k < 4; ++k) {
        if (pok[k]) {
            int px = pg + 16 * k;
            f32x4 o = acc4[k] * inv;
            *(f32x4*)(zq + px * CIT + ch4) = o;   // d = 16*px + ch (pixel-major)
        }
    }
}

// K4: fold (overlap-add) + count-divide + 1x1 out conv + residual.
// Zp layout [gq][d] with d = 16*(i*7+j) + c  -> 16-consecutive-float reads per position.
__global__ __launch_bounds__(256) void k_fold(
    const float* __restrict__ bin, const float* __restrict__ ow,
    const float* __restrict__ ob, const float* __restrict__ Zp,
    float* __restrict__ outp)
{
    int p = blockIdx.x * 256 + threadIdx.x;
    if (p >= NB * HH * WW) return;
    int ox = p % WW; int r = p / WW; int oy = r % HH; int bb = r / HH;
    int yp = oy + PAD, xp = ox + PAD;
    int qh0 = (yp - 3) >> 2, qh1 = min(31, yp >> 2);
    int qw0 = (xp - 3) >> 2, qw1 = min(31, xp >> 2);
    float cnt = (float)((qh1 - qh0 + 1) * (qw1 - qw0 + 1));
    float y16[CIT];
    #pragma unroll
    for (int c = 0; c < CIT; ++c) y16[c] = 0.f;
    for (int qhh = qh0; qhh <= qh1; ++qhh) {
        int i = yp - 4 * qhh;
        for (int qww = qw0; qww <= qw1; ++qww) {
            int j = xp - 4 * qww;
            const float* zb = Zp + (size_t)((bb << 10) + qhh * 32 + qww) * DD + (i * 7 + j) * CIT;
            #pragma unroll
            for (int c = 0; c < CIT; ++c) y16[c] += zb[c];
        }
    }
    float icnt = 1.f / cnt;
    #pragma unroll
    for (int c = 0; c < CIT; ++c) y16[c] *= icnt;
    size_t oidx = ((size_t)(bb * CIN) * HH + oy) * WW + ox;
    for (int co = 0; co < CIN; ++co) {
        float a = ob[co];
        #pragma unroll
        for (int c = 0; c < CIT; ++c) a += ow[co * CIT + c] * y16[c];
        outp[oidx + (size_t)co * HH * WW] = bin[oidx + (size_t)co * HH * WW] + a;
    }
}

extern "C" void kernel_launch(void* const* d_in, const int* in_sizes, int n_in,
                              void* d_out, int out_size, void* d_ws, size_t ws_size,
                              hipStream_t stream) {
    (void)in_sizes; (void)n_in; (void)out_size; (void)ws_size;
    const float* bin = (const float*)d_in[0];
    const float* gw  = (const float*)d_in[1];
    const float* gb  = (const float*)d_in[2];
    const float* tw  = (const float*)d_in[3];
    const float* tb  = (const float*)d_in[4];
    const float* pw  = (const float*)d_in[5];
    const float* pb  = (const float*)d_in[6];
    const float* ow  = (const float*)d_in[7];
    const float* ob  = (const float*)d_in[8];

    float* outp = (float*)d_out;
    // d_out scratch (consumed before k_fold writes outp): 14.0 MB of 16.78 MB
    float* b3f = outp;                                        // NHWCF floats
    float* b1f = outp + NHWCF;                                // NHWCF floats
    unsigned short* b3n = (unsigned short*)(outp + 2 * (size_t)NHWCF);  // NHWCF shorts
    unsigned short* b1n = b3n + NHWCF;                        // NHWCF shorts

    float* ws = (float*)d_ws;                                 // 25.9 MB total
    float* b2f = ws;                                          // NHWCF floats
    float* Zp  = ws + NHWCF;                                  // NB*L1*DD floats
    _Float16* tmaxh = (_Float16*)(ws + NHWCF + (size_t)NB * L1 * DD);  // 4096*1024 fp16

    hipLaunchKernelGGL(k_prep, dim3((NB * NPIX + 255) / 256), dim3(256), 0, stream,
                       bin, gw, gb, tw, tb, pw, pb, b1f, b2f, b3f, b1n, b3n);
    hipLaunchKernelGGL(k_screen, dim3(512), dim3(512), 0, stream,
                       b1n, b3n, tmaxh);
    hipLaunchKernelGGL(k_finalize, dim3(1024), dim3(256), 0, stream,
                       b1f, b2f, b3f, tmaxh, Zp);
    hipLaunchKernelGGL(k_fold, dim3((NB * HH * WW + 255) / 256), dim3(256), 0, stream,
                       bin, ow, ob, Zp, outp);
}